// Round 3
// baseline (241.523 us; speedup 1.0000x reference)
//
#include <hip/hip_runtime.h>
#include <stdint.h>

#define SEQ   2048
#define DIM   1024
#define BATCH 4

typedef _Float16 f16;
typedef __attribute__((ext_vector_type(8))) _Float16 f16x8;
typedef __attribute__((ext_vector_type(4))) _Float16 f16x4;
typedef __attribute__((ext_vector_type(4))) float   f32x4;

typedef void __attribute__((address_space(1))) vg_t;
typedef void __attribute__((address_space(3))) vl_t;

__device__ __forceinline__ void gld16(const void* g, void* l) {
  // async global->LDS, 16B per lane; LDS dest = wave-uniform base + lane*16
  __builtin_amdgcn_global_load_lds((vg_t*)g, (vl_t*)l, 16, 0, 0);
}

// ---------------------------------------------------------------------------
// Fused fp32->fp16 convert of x, Wq, Wk, Wv in ONE dispatch.
// ---------------------------------------------------------------------------
__global__ __launch_bounds__(256) void cvt_all(const float* __restrict__ x,
                                               const float* __restrict__ wq,
                                               const float* __restrict__ wk,
                                               const float* __restrict__ wv,
                                               f16* __restrict__ xb,
                                               f16* __restrict__ wh) {
  const int bx = blockIdx.x;
  const float* in; f16* out; int base;
  if (bx < 8192)       { in = x;  out = xb;             base = bx; }
  else if (bx < 9216)  { in = wq; out = wh;             base = bx - 8192; }
  else if (bx < 10240) { in = wk; out = wh + (1 << 20); base = bx - 9216; }
  else                 { in = wv; out = wh + (2 << 20); base = bx - 10240; }
  const long i = ((long)base * 256 + threadIdx.x) * 4;
  float4 v = *(const float4*)(in + i);
  f16x4 o = { (f16)v.x, (f16)v.y, (f16)v.z, (f16)v.w };
  *(f16x4*)(out + i) = o;
}

// ---------------------------------------------------------------------------
// QKV projection, pipelined: BM=128 x BN=256 tiles -> 64x12 = 768 blocks
// = EXACTLY 3 rounds of 256 CUs (round-2's 256^2 had 384 tiles = 1.5 rounds,
// so round 2 ran half-idle: 75% capacity ceiling -> measured 75.6us).
// 512 thr / 8 waves (2M x 4N, wave 64x64, acc 4x4 = 64 VGPR), BK=64.
// TRIPLE-buffered LDS (3 x 48 KiB = 144 KiB): tile T+2 staged (6 gld16 units
// of 8 KiB) during tile T's two phases; counted VMW(6) once per tile leaves
// exactly the next tile's 6 issues in flight -> wait-to-issue gap >= 2 phases.
// Phase = template density: 16 MFMA + 8 ds_read_b128 + 3 stage + 2 s_barrier.
// Chunk-XOR swizzle (T2) on stage-source and ds_read (both-sides, rule 21).
// ---------------------------------------------------------------------------
__global__ __launch_bounds__(512, 2) void qkv_p3(const f16* __restrict__ A,
                                                 const f16* __restrict__ B,
                                                 f16* __restrict__ Qh) {
  __shared__ __align__(16) f16 ls[3][24576];  // per buf: A 128x64 | B 256x64

  const int tid  = threadIdx.x;
  const int wave = tid >> 6;
  const int lane = tid & 63;
  const int fr   = lane & 15;
  const int fq   = lane >> 4;

  // XCD-chunked swizzle: XCD x owns m-tiles [8x, 8x+8) x all 12 n-tiles
  // -> per-XCD A slice = 2 MB (L2-resident); B streams via LLC.
  const int lin = blockIdx.x;
  const int swz = (lin & 7) * 96 + (lin >> 3);
  const int m0  = (swz / 12) * 128;
  const int n0  = (swz % 12) * 256;

  const f16* Ab = A + (long)m0 * DIM;
  const f16* Bb = B + (long)n0 * DIM;

  const int wm = (wave & 1) * 64;    // wave's 64 rows of the 128-row tile
  const int wn = (wave >> 1) * 64;   // wave's 64 cols of the 256-col tile

  f32x4 acc[4][4] = {};
  f16x8 af[4], bf[4];

  // stage unit c of tile t: c<2 -> A rows [c*64, c*64+64); c>=2 -> B rows
  // [(c-2)*64, ...). 512 lanes x 16B = 8 KiB = 64 rows of 64 f16.
#define STAGE(t, c)                                                            \
  {                                                                            \
    const int rr_ = tid >> 3, sj_ = tid & 7;                                   \
    f16* lb_ = &ls[(t) % 3][0];                                                \
    if ((c) < 2) {                                                             \
      const int row_ = (c) * 64 + rr_;                                         \
      gld16(Ab + (long)row_ * DIM + (t) * 64 + ((sj_ ^ (row_ & 7)) << 3),      \
            (void*)(lb_ + (c) * 4096 + tid * 8));                              \
    } else {                                                                   \
      const int row_ = ((c) - 2) * 64 + rr_;                                   \
      gld16(Bb + (long)row_ * DIM + (t) * 64 + ((sj_ ^ (row_ & 7)) << 3),      \
            (void*)(lb_ + 8192 + ((c) - 2) * 4096 + tid * 8));                 \
    }                                                                          \
  }

#define LDF(p, ks)                                                             \
  {                                                                            \
    const f16* lAx_ = &ls[p][0];                                               \
    const f16* lBx_ = &ls[p][8192];                                            \
    _Pragma("unroll") for (int mi_ = 0; mi_ < 4; ++mi_) {                      \
      const int r_ = wm + mi_ * 16 + fr;                                       \
      af[mi_] = *(const f16x8*)(lAx_ + r_ * 64 +                               \
                                ((((ks) * 4 + fq) ^ (r_ & 7)) << 3));          \
    }                                                                          \
    _Pragma("unroll") for (int ni_ = 0; ni_ < 4; ++ni_) {                      \
      const int r_ = wn + ni_ * 16 + fr;                                       \
      bf[ni_] = *(const f16x8*)(lBx_ + r_ * 64 +                               \
                                ((((ks) * 4 + fq) ^ (r_ & 7)) << 3));          \
    }                                                                          \
  }

#define MMAC()                                                                 \
  {                                                                            \
    __builtin_amdgcn_s_setprio(1);                                             \
    _Pragma("unroll") for (int mi_ = 0; mi_ < 4; ++mi_)                        \
    _Pragma("unroll") for (int ni_ = 0; ni_ < 4; ++ni_)                        \
      acc[mi_][ni_] = __builtin_amdgcn_mfma_f32_16x16x32_f16(                  \
          af[mi_], bf[ni_], acc[mi_][ni_], 0, 0, 0);                           \
    __builtin_amdgcn_s_setprio(0);                                             \
  }

#define BAR() __builtin_amdgcn_s_barrier()
#define VMW(n) asm volatile("s_waitcnt vmcnt(" #n ")" ::: "memory")

  // prologue: stage tiles 0,1 (12 units); VMW(6) -> tile0 landed, tile1 flying
#pragma unroll
  for (int c = 0; c < 6; ++c) STAGE(0, c);
#pragma unroll
  for (int c = 0; c < 6; ++c) STAGE(1, c);
  VMW(6);
  BAR();

  // Ledger (steady state, tile T in buf T%3):
  //   ph_a: LD buf[T] ks0 | stage T+2 units 0-2 | BAR MM BAR
  //   ph_b: LD buf[T] ks1 | stage T+2 units 3-5 | BAR MM VMW(6) BAR
  // VMW(6) leaves exactly T+2's 6 issues outstanding -> T+1 (staged during
  // T-1, >=2 phases ago) is complete before ph_a(T+1) reads it. buf (T+2)%3
  // was last read in T-1's phases, whose final BAR precedes these stages.
#pragma unroll
  for (int t = 0; t < 14; ++t) {
    LDF(t % 3, 0);
    STAGE(t + 2, 0); STAGE(t + 2, 1); STAGE(t + 2, 2);
    BAR(); MMAC(); BAR();
    LDF(t % 3, 1);
    STAGE(t + 2, 3); STAGE(t + 2, 4); STAGE(t + 2, 5);
    BAR(); MMAC(); VMW(6); BAR();
  }
  // t = 14: no staging; VMW(0) -> tile 15 (issued during t=13) landed
  LDF(2, 0); BAR(); MMAC(); BAR();
  LDF(2, 1); BAR(); MMAC(); VMW(0); BAR();
  // t = 15
  LDF(0, 0); BAR(); MMAC(); BAR();
  LDF(0, 1); BAR(); MMAC();

#undef STAGE
#undef LDF
#undef MMAC
#undef BAR
#undef VMW

  // Epilogue: n0 spans exactly one of {Q,K,V} (256 | 1024). C/D layout:
  // col = lane&15, row = (lane>>4)*4 + reg.
  f16* Kh = Qh + (size_t)8 * 1024 * 1024;
  f16* VT = Kh + (size_t)8 * 1024 * 1024;
#pragma unroll
  for (int mi = 0; mi < 4; ++mi) {
    const int row = m0 + wm + mi * 16 + fq * 4;
#pragma unroll
    for (int ni = 0; ni < 4; ++ni) {
      const int col = n0 + wn + ni * 16 + fr;
      if (n0 < 1024) {
#pragma unroll
        for (int r = 0; r < 4; ++r) Qh[(long)(row + r) * DIM + col] = (f16)acc[mi][ni][r];
      } else if (n0 < 2048) {
#pragma unroll
        for (int r = 0; r < 4; ++r) Kh[(long)(row + r) * DIM + (col - 1024)] = (f16)acc[mi][ni][r];
      } else {
        f16x4 o = { (f16)acc[mi][ni][0], (f16)acc[mi][ni][1],
                    (f16)acc[mi][ni][2], (f16)acc[mi][ni][3] };
        *(f16x4*)(VT + (long)(col - 2048) * (BATCH * SEQ) + row) = o;
      }
    }
  }
}

// ---------------------------------------------------------------------------
// NT GEMM: C[m,n] = sum_k A[m,k]*B[n,k], fp16 in, fp32 accumulate.
// 128x128 tile, 4 waves (2x2 of 64x64), 16x16x32 MFMA, BK template.
// MODE: 0 fp32 row-major, 1 fp16 row-major, 2 fp16 transposed.
// CAUSAL: 0 none, 1 skip tiles above diagonal (scores), 2 K-limit m0+128 (PV),
//         3 PV with balanced 1D grid (512 blocks): grid (16,8,4) round-robin
//         puts SAME-Keff pairs on one CU (b%16 == (b+256)%16) -> 1.88x makespan;
//         anti-symmetric longest<->shortest pairing makes per-CU Keff-sum const.
// BK=128 here: scores/PV grids are ~2 blocks/CU GRID-limited, so BK=64 buys no
// occupancy and doubles barrier drains (round-1 regression).
// ---------------------------------------------------------------------------
template <int MODE, int CAUSAL, int BK>
__global__ __launch_bounds__(256) void gemm_bt(const f16* __restrict__ A, int lda, long aOffZ,
                                               const f16* __restrict__ B, int ldb, long bOffZ,
                                               void* __restrict__ Cv, int ldc, long cOffZ,
                                               int K) {
  constexpr int CH  = BK / 8;    // 16B chunks per row
  constexpr int RPL = 64 / CH;   // rows per wave-load
  constexpr int NL  = 32 / RPL;  // wave-loads per tile per wave
  __shared__ __align__(16) f16 lA[128 * BK];
  __shared__ __align__(16) f16 lB[128 * BK];

  const int tid  = threadIdx.x;
  const int wave = tid >> 6;
  const int lane = tid & 63;

  int m0, n0, z;
  if (CAUSAL == 3) {
    const int id   = blockIdx.x;
    const int item = (id < 256) ? id : 767 - id;
    const int mt   = 15 - (item >> 5);     // 32 blocks per Keff group
    const int j    = item & 31;
    m0 = mt * 128;
    n0 = (j & 7) * 128;
    z  = j >> 3;
  } else {
    m0 = blockIdx.x * 128;
    n0 = blockIdx.y * 128;
    z  = blockIdx.z;
  }

  if (CAUSAL == 1 && n0 >= m0 + 128) return;
  const int Keff = (CAUSAL >= 2) ? (m0 + 128) : K;

  const f16* Ab = A + (long)z * aOffZ + (long)m0 * lda;
  const f16* Bb = B + (long)z * bOffZ + (long)n0 * ldb;

  const int wm = (wave & 1) * 64;
  const int wn = (wave >> 1) * 64;

  f32x4 acc[4][4] = {};

  const int srow = lane / CH;
  const int sj   = lane % CH;
  const int fr   = lane & 15;
  const int fq   = lane >> 4;

  for (int kt = 0; kt < Keff; kt += BK) {
    __syncthreads();  // previous iteration's ds_reads done
#pragma unroll
    for (int j = 0; j < NL; ++j) {
      const int rgrp = j * 4 + wave;
      const int row  = rgrp * RPL + srow;
      const int gch  = sj ^ (row & (CH - 1));
      gld16(Ab + (long)row * lda + kt + gch * 8, (void*)(lA + rgrp * 512 + lane * 8));
      gld16(Bb + (long)row * ldb + kt + gch * 8, (void*)(lB + rgrp * 512 + lane * 8));
    }
    __syncthreads();  // vmcnt drained -> staging visible

#pragma unroll
    for (int kk = 0; kk < BK; kk += 32) {
      f16x8 af[4], bf[4];
#pragma unroll
      for (int i = 0; i < 4; ++i) {
        const int arow = wm + i * 16 + fr;
        const int ach  = (kk / 8 + fq) ^ (arow & (CH - 1));
        af[i] = *(const f16x8*)(lA + arow * BK + ach * 8);
        const int brow = wn + i * 16 + fr;
        const int bch  = (kk / 8 + fq) ^ (brow & (CH - 1));
        bf[i] = *(const f16x8*)(lB + brow * BK + bch * 8);
      }
#pragma unroll
      for (int mi = 0; mi < 4; ++mi)
#pragma unroll
        for (int ni = 0; ni < 4; ++ni)
          acc[mi][ni] = __builtin_amdgcn_mfma_f32_16x16x32_f16(af[mi], bf[ni], acc[mi][ni], 0, 0, 0);
    }
  }

  // Epilogue. C/D layout: col = lane&15, row = (lane>>4)*4 + reg
#pragma unroll
  for (int mi = 0; mi < 4; ++mi) {
    const int row = m0 + wm + mi * 16 + fq * 4;
#pragma unroll
    for (int ni = 0; ni < 4; ++ni) {
      const int col = n0 + wn + ni * 16 + fr;
      if constexpr (MODE == 0) {
        float* C = (float*)Cv + (long)z * cOffZ;
#pragma unroll
        for (int r = 0; r < 4; ++r) C[(long)(row + r) * ldc + col] = acc[mi][ni][r];
      } else if constexpr (MODE == 1) {
        f16* C = (f16*)Cv + (long)z * cOffZ;
#pragma unroll
        for (int r = 0; r < 4; ++r) C[(long)(row + r) * ldc + col] = (f16)acc[mi][ni][r];
      } else {  // MODE 2
        f16* C = (f16*)Cv + (long)z * cOffZ;
        f16x4 o = { (f16)acc[mi][ni][0], (f16)acc[mi][ni][1],
                    (f16)acc[mi][ni][2], (f16)acc[mi][ni][3] };
        *(f16x4*)(C + (long)col * ldc + row) = o;
      }
    }
  }
}

// ---------------------------------------------------------------------------
// Causal softmax over f16 score rows, in-place (zero above diagonal).
// grid = (SEQ, BATCH), block = 256, 8 contiguous elems/thread (f16x8).
// Threads entirely above the diagonal skip the load; writes stay full.
// ---------------------------------------------------------------------------
__global__ __launch_bounds__(256) void softmax_causal(f16* S) {
  const int q = blockIdx.x, b = blockIdx.y;
  f16* row = S + ((long)b * SEQ + q) * SEQ;
  const int tid = threadIdx.x;
  const int lane = tid & 63, wave = tid >> 6;
  const int nvalid = q + 1;

  f16x8 vv = {};
  if (tid * 8 < nvalid) vv = *(const f16x8*)(row + tid * 8);
  float v[8];
  float m = -3.0e38f;
#pragma unroll
  for (int i = 0; i < 8; ++i) {
    const int k = tid * 8 + i;
    v[i] = (k < nvalid) ? (float)vv[i] * 0.03125f : -3.0e38f;
    m = fmaxf(m, v[i]);
  }
#pragma unroll
  for (int off = 32; off; off >>= 1) m = fmaxf(m, __shfl_xor(m, off));
  __shared__ float redm[4], reds[4];
  if (lane == 0) redm[wave] = m;
  __syncthreads();
  m = fmaxf(fmaxf(redm[0], redm[1]), fmaxf(redm[2], redm[3]));

  float s = 0.f;
#pragma unroll
  for (int i = 0; i < 8; ++i) {
    const float p = (v[i] > -1.0e37f) ? __expf(v[i] - m) : 0.f;
    v[i] = p;
    s += p;
  }
#pragma unroll
  for (int off = 32; off; off >>= 1) s += __shfl_xor(s, off);
  if (lane == 0) reds[wave] = s;
  __syncthreads();
  s = reds[0] + reds[1] + reds[2] + reds[3];
  const float inv = 1.f / s;
  f16x8 o;
#pragma unroll
  for (int i = 0; i < 8; ++i) o[i] = (f16)(v[i] * inv);
  *(f16x8*)(row + tid * 8) = o;
}

// ---------------------------------------------------------------------------
extern "C" void kernel_launch(void* const* d_in, const int* in_sizes, int n_in,
                              void* d_out, int out_size, void* d_ws, size_t ws_size,
                              hipStream_t stream) {
  const float* x  = (const float*)d_in[0];
  const float* Wq = (const float*)d_in[1];
  const float* Wk = (const float*)d_in[2];
  const float* Wv = (const float*)d_in[3];
  float* out = (float*)d_out;

  // ws layout (f16 elems): xb 8M | Wh 3M | Qh 8M | Kh 8M | VT 8M ([1024][8192]) |
  //                        Sc 16M f16 scores->probs in place (4 x 2048 x 2048)
  if (ws_size < (size_t)51 * 1024 * 1024 * 2) return;

  f16* xb = (f16*)d_ws;
  f16* Wh = xb + (size_t)8 * 1024 * 1024;
  f16* Qh = Wh + (size_t)3 * 1024 * 1024;
  f16* Kh = Qh + (size_t)8 * 1024 * 1024;
  f16* VT = Kh + (size_t)8 * 1024 * 1024;
  f16* Sc = VT + (size_t)8 * 1024 * 1024;

  const long QOFF = (long)SEQ * DIM;  // per-batch Q/K offset
  const long SOFF = (long)SEQ * SEQ;  // per-batch score offset (f16 elems)

  cvt_all<<<11264, 256, 0, stream>>>(x, Wq, Wk, Wv, xb, Wh);

  // Fused QKV: M=8192, N=3072, K=1024 -- 128x256 tiles, 768 blocks = 3 exact
  // rounds, triple-buffered counted-vmcnt pipeline.
  qkv_p3<<<768, 512, 0, stream>>>(xb, Wh, Qh);

  // scores = Q K^T (causal block-skip), f16 out, BK=128 (grid-limited occupancy)
  gemm_bt<1, 1, 128><<<dim3(16, 16, 4), 256, 0, stream>>>(Qh, DIM, QOFF, Kh, DIM, QOFF,
                                                          Sc, SEQ, SOFF, DIM);

  // causal softmax (scale 1/32), in-place f16 probs, zero above diagonal
  softmax_causal<<<dim3(SEQ, BATCH), 256, 0, stream>>>(Sc);

  // Z = P V  (A = probs f16 ld 2048; B = VT ld 8192; per-M-tile K-limit),
  // BK=128 + balanced 1D grid (longest<->shortest pairing kills the Keff tail)
  gemm_bt<0, 3, 128><<<dim3(512, 1, 1), 256, 0, stream>>>(Sc, SEQ, SOFF,
                                                          VT, BATCH * SEQ, SEQ,
                                                          out, DIM, (long)SEQ * DIM, SEQ);
}

// Round 4
// 238.632 us; speedup vs baseline: 1.0121x; 1.0121x over previous
//
#include <hip/hip_runtime.h>
#include <stdint.h>

#define SEQ   2048
#define DIM   1024
#define BATCH 4

typedef _Float16 f16;
typedef __attribute__((ext_vector_type(8))) _Float16 f16x8;
typedef __attribute__((ext_vector_type(4))) _Float16 f16x4;
typedef __attribute__((ext_vector_type(4))) float   f32x4;

typedef void __attribute__((address_space(1))) vg_t;
typedef void __attribute__((address_space(3))) vl_t;

__device__ __forceinline__ void gld16(const void* g, void* l) {
  // async global->LDS, 16B per lane; LDS dest = wave-uniform base + lane*16
  __builtin_amdgcn_global_load_lds((vg_t*)g, (vl_t*)l, 16, 0, 0);
}

// ---------------------------------------------------------------------------
// Fused fp32->fp16 convert of x, Wq, Wk, Wv in ONE dispatch.
// ---------------------------------------------------------------------------
__global__ __launch_bounds__(256) void cvt_all(const float* __restrict__ x,
                                               const float* __restrict__ wq,
                                               const float* __restrict__ wk,
                                               const float* __restrict__ wv,
                                               f16* __restrict__ xb,
                                               f16* __restrict__ wh) {
  const int bx = blockIdx.x;
  const float* in; f16* out; int base;
  if (bx < 8192)       { in = x;  out = xb;             base = bx; }
  else if (bx < 9216)  { in = wq; out = wh;             base = bx - 8192; }
  else if (bx < 10240) { in = wk; out = wh + (1 << 20); base = bx - 9216; }
  else                 { in = wv; out = wh + (2 << 20); base = bx - 10240; }
  const long i = ((long)base * 256 + threadIdx.x) * 4;
  float4 v = *(const float4*)(in + i);
  f16x4 o = { (f16)v.x, (f16)v.y, (f16)v.z, (f16)v.w };
  *(f16x4*)(out + i) = o;
}

// ---------------------------------------------------------------------------
// QKV projection: 256(M) x 192(N) tiles -> 32 x 16 = 512 blocks = EXACTLY
// 2 rounds of 256 CUs (r3's 128x256 had 3 exact rounds but only 4.2 MF per
// K-tile against a ~1900-cyc fixed phase overhead; 6.29 MF/K-tile amortizes
// it: predicted ~3700 cyc/K-tile -> ~1010 TF).
// 512 thr / 8 waves (2M x 4N, wave 128x48, acc 8x3 = 96 VGPR), BK=64.
// LDS 136 KiB: A double-buffered (2 x 32 KiB, stage-ahead 1), B triple-
// buffered (3 x 24 KiB, stage-ahead 2). Counted VMW(3) per tile (T4, never
// 0 in main loop): issue order per tile t = [A(t+1) x4 in ph_a, B(t+2) x3 in
// ph_b], so at each tile boundary the 3 newest outstanding = B(t+2); VMW(3)
// proves A(t+1), B(t+1) landed. Chunk-XOR swizzle (T2) both-sides (rule 21).
// ---------------------------------------------------------------------------
__global__ __launch_bounds__(512, 2) void qkv_192(const f16* __restrict__ A,
                                                  const f16* __restrict__ B,
                                                  f16* __restrict__ Qh) {
  __shared__ __align__(16) f16 sA[2][16384];  // [256 rows][64 k]
  __shared__ __align__(16) f16 sB[3][12288];  // [192 rows][64 k]

  const int tid  = threadIdx.x;
  const int wave = tid >> 6;
  const int lane = tid & 63;
  const int fr   = lane & 15;
  const int fq   = lane >> 4;
  const int rr   = tid >> 3;   // staging row-within-unit
  const int sj   = tid & 7;    // staging chunk

  // XCD-chunked swizzle: XCD x (= id mod 8 under round-robin dispatch) owns
  // m-tiles [4x, 4x+4) x all 16 n-tiles in BOTH rounds -> per-XCD A slice
  // = 4 x 256 rows x 2 KB = 2 MB (L2-resident); B (6 MB) streams via LLC.
  const int id  = blockIdx.x;
  const int swz = (id & 7) * 64 + (id >> 3);
  const int m0  = (swz >> 4) * 256;
  const int n0  = (swz & 15) * 192;

  const f16* Ab = A + (long)m0 * DIM;
  const f16* Bb = B + (long)n0 * DIM;

  const int wm = (wave & 1) * 128;   // wave's 128 rows of 256
  const int wn = (wave >> 1) * 48;   // wave's 48 cols of 192

  f32x4 acc[8][3] = {};
  f16x8 af[8], bf[3];

#define STAGE_A(t)                                                             \
  {                                                                            \
    _Pragma("unroll") for (int u_ = 0; u_ < 4; ++u_) {                         \
      const int row_ = u_ * 64 + rr;                                           \
      gld16(Ab + (long)row_ * DIM + (t) * 64 + ((sj ^ (row_ & 7)) << 3),       \
            (void*)(&sA[(t) & 1][0] + u_ * 4096 + tid * 8));                   \
    }                                                                          \
  }
#define STAGE_B(t)                                                             \
  {                                                                            \
    _Pragma("unroll") for (int u_ = 0; u_ < 3; ++u_) {                         \
      const int row_ = u_ * 64 + rr;                                           \
      gld16(Bb + (long)row_ * DIM + (t) * 64 + ((sj ^ (row_ & 7)) << 3),       \
            (void*)(&sB[(t) % 3][0] + u_ * 4096 + tid * 8));                   \
    }                                                                          \
  }
#define LDFA(pa, ks)                                                           \
  {                                                                            \
    _Pragma("unroll") for (int mi_ = 0; mi_ < 8; ++mi_) {                      \
      const int r_ = wm + mi_ * 16 + fr;                                       \
      af[mi_] = *(const f16x8*)(&sA[pa][0] + r_ * 64 +                         \
                                ((((ks) * 4 + fq) ^ (r_ & 7)) << 3));          \
    }                                                                          \
  }
#define LDFB(pb, ks)                                                           \
  {                                                                            \
    _Pragma("unroll") for (int ni_ = 0; ni_ < 3; ++ni_) {                      \
      const int r_ = wn + ni_ * 16 + fr;                                       \
      bf[ni_] = *(const f16x8*)(&sB[pb][0] + r_ * 64 +                         \
                                ((((ks) * 4 + fq) ^ (r_ & 7)) << 3));          \
    }                                                                          \
  }
#define MM()                                                                   \
  {                                                                            \
    __builtin_amdgcn_s_setprio(1);                                             \
    _Pragma("unroll") for (int mi_ = 0; mi_ < 8; ++mi_)                        \
    _Pragma("unroll") for (int ni_ = 0; ni_ < 3; ++ni_)                        \
      acc[mi_][ni_] = __builtin_amdgcn_mfma_f32_16x16x32_f16(                  \
          af[mi_], bf[ni_], acc[mi_][ni_], 0, 0, 0);                           \
    __builtin_amdgcn_s_setprio(0);                                             \
  }
#define BAR() __builtin_amdgcn_s_barrier()
#define VMW(n) asm volatile("s_waitcnt vmcnt(" #n ")" ::: "memory")

  // prologue: A(0) 4u + B(0) 3u + B(1) 3u = 10 issues; VMW(3) drains the 7
  // oldest (= A0,B0), leaves B(1) in flight.
  STAGE_A(0); STAGE_B(0); STAGE_B(1);
  VMW(3);
  BAR();

  // Ledger per tile t (buf A: t&1, B: t%3):
  //   ph_a: LDF(ks0) | STAGE_A(t+1)        | BAR MM BAR
  //   ph_b: LDF(ks1) | STAGE_B(t+2)        | BAR MM VMW(3) BAR
  // Write-hazards: A(t+1)->sA[(t+1)&1] holds A(t-1), last read t-1 ph_b (its
  // lgkm wait precedes that phase's end-BAR). B(t+2)->sB[(t+2)%3] holds
  // B(t-1), same argument. VMW(3): newest 3 outstanding = B(t+2) trio.
#pragma unroll
  for (int t = 0; t < 14; ++t) {
    LDFA(t & 1, 0); LDFB(t % 3, 0);
    STAGE_A(t + 1);
    BAR(); MM(); BAR();
    LDFA(t & 1, 1); LDFB(t % 3, 1);
    STAGE_B(t + 2);
    BAR(); MM(); VMW(3); BAR();
  }
  // t = 14: stage A(15) only; VMW(0) -> A(15), B(15) landed
  LDFA(0, 0); LDFB(2, 0);
  STAGE_A(15);
  BAR(); MM(); BAR();
  LDFA(0, 1); LDFB(2, 1);
  BAR(); MM(); VMW(0); BAR();
  // t = 15: pure compute
  LDFA(1, 0); LDFB(0, 0);
  BAR(); MM(); BAR();
  LDFA(1, 1); LDFB(0, 1);
  BAR(); MM();

#undef STAGE_A
#undef STAGE_B
#undef LDFA
#undef LDFB
#undef MM
#undef BAR
#undef VMW

  // Epilogue. C/D layout: col = lane&15, row = (lane>>4)*4 + reg. n0=nt*192
  // tiles straddle the 1024-boundaries only at 16-col-frag granularity; the
  // region branch is per-frag and wave-uniform (boundaries are mult. of 16).
  f16* Kh = Qh + (size_t)8 * 1024 * 1024;
  f16* VT = Kh + (size_t)8 * 1024 * 1024;
#pragma unroll
  for (int mi = 0; mi < 8; ++mi) {
    const int row = m0 + wm + mi * 16 + fq * 4;
#pragma unroll
    for (int ni = 0; ni < 3; ++ni) {
      const int col = n0 + wn + ni * 16 + fr;
      if (col < 1024) {
#pragma unroll
        for (int r = 0; r < 4; ++r) Qh[(long)(row + r) * DIM + col] = (f16)acc[mi][ni][r];
      } else if (col < 2048) {
#pragma unroll
        for (int r = 0; r < 4; ++r) Kh[(long)(row + r) * DIM + (col - 1024)] = (f16)acc[mi][ni][r];
      } else {
        f16x4 o = { (f16)acc[mi][ni][0], (f16)acc[mi][ni][1],
                    (f16)acc[mi][ni][2], (f16)acc[mi][ni][3] };
        *(f16x4*)(VT + (long)(col - 2048) * (BATCH * SEQ) + row) = o;
      }
    }
  }
}

// ---------------------------------------------------------------------------
// NT GEMM: C[m,n] = sum_k A[m,k]*B[n,k], fp16 in, fp32 accumulate.
// 128x128 tile, 4 waves (2x2 of 64x64), 16x16x32 MFMA, BK template.
// MODE: 0 fp32 row-major, 1 fp16 row-major, 2 fp16 transposed.
// CAUSAL: 0 none, 1 skip tiles above diagonal (scores), 2 K-limit m0+128 (PV),
//         3 PV with balanced 1D grid (512 blocks): anti-symmetric longest<->
//         shortest pairing -> per-CU Keff-sum constant (grid-order round-robin
//         pairs SAME-Keff blocks -> 1.88x makespan).
// BK=128: scores/PV grids are ~2 blocks/CU grid-limited; BK=64 doubles
// barrier drains for no occupancy gain (r1 regression).
// ---------------------------------------------------------------------------
template <int MODE, int CAUSAL, int BK>
__global__ __launch_bounds__(256) void gemm_bt(const f16* __restrict__ A, int lda, long aOffZ,
                                               const f16* __restrict__ B, int ldb, long bOffZ,
                                               void* __restrict__ Cv, int ldc, long cOffZ,
                                               int K) {
  constexpr int CH  = BK / 8;    // 16B chunks per row
  constexpr int RPL = 64 / CH;   // rows per wave-load
  constexpr int NL  = 32 / RPL;  // wave-loads per tile per wave
  __shared__ __align__(16) f16 lA[128 * BK];
  __shared__ __align__(16) f16 lB[128 * BK];

  const int tid  = threadIdx.x;
  const int wave = tid >> 6;
  const int lane = tid & 63;

  int m0, n0, z;
  if (CAUSAL == 3) {
    const int id   = blockIdx.x;
    const int item = (id < 256) ? id : 767 - id;
    const int mt   = 15 - (item >> 5);     // 32 blocks per Keff group
    const int j    = item & 31;
    m0 = mt * 128;
    n0 = (j & 7) * 128;
    z  = j >> 3;
  } else {
    m0 = blockIdx.x * 128;
    n0 = blockIdx.y * 128;
    z  = blockIdx.z;
  }

  if (CAUSAL == 1 && n0 >= m0 + 128) return;
  const int Keff = (CAUSAL >= 2) ? (m0 + 128) : K;

  const f16* Ab = A + (long)z * aOffZ + (long)m0 * lda;
  const f16* Bb = B + (long)z * bOffZ + (long)n0 * ldb;

  const int wm = (wave & 1) * 64;
  const int wn = (wave >> 1) * 64;

  f32x4 acc[4][4] = {};

  const int srow = lane / CH;
  const int sj   = lane % CH;
  const int fr   = lane & 15;
  const int fq   = lane >> 4;

  for (int kt = 0; kt < Keff; kt += BK) {
    __syncthreads();  // previous iteration's ds_reads done
#pragma unroll
    for (int j = 0; j < NL; ++j) {
      const int rgrp = j * 4 + wave;
      const int row  = rgrp * RPL + srow;
      const int gch  = sj ^ (row & (CH - 1));
      gld16(Ab + (long)row * lda + kt + gch * 8, (void*)(lA + rgrp * 512 + lane * 8));
      gld16(Bb + (long)row * ldb + kt + gch * 8, (void*)(lB + rgrp * 512 + lane * 8));
    }
    __syncthreads();  // vmcnt drained -> staging visible

#pragma unroll
    for (int kk = 0; kk < BK; kk += 32) {
      f16x8 af[4], bf[4];
#pragma unroll
      for (int i = 0; i < 4; ++i) {
        const int arow = wm + i * 16 + fr;
        const int ach  = (kk / 8 + fq) ^ (arow & (CH - 1));
        af[i] = *(const f16x8*)(lA + arow * BK + ach * 8);
        const int brow = wn + i * 16 + fr;
        const int bch  = (kk / 8 + fq) ^ (brow & (CH - 1));
        bf[i] = *(const f16x8*)(lB + brow * BK + bch * 8);
      }
#pragma unroll
      for (int mi = 0; mi < 4; ++mi)
#pragma unroll
        for (int ni = 0; ni < 4; ++ni)
          acc[mi][ni] = __builtin_amdgcn_mfma_f32_16x16x32_f16(af[mi], bf[ni], acc[mi][ni], 0, 0, 0);
    }
  }

  // Epilogue. C/D layout: col = lane&15, row = (lane>>4)*4 + reg
#pragma unroll
  for (int mi = 0; mi < 4; ++mi) {
    const int row = m0 + wm + mi * 16 + fq * 4;
#pragma unroll
    for (int ni = 0; ni < 4; ++ni) {
      const int col = n0 + wn + ni * 16 + fr;
      if constexpr (MODE == 0) {
        float* C = (float*)Cv + (long)z * cOffZ;
#pragma unroll
        for (int r = 0; r < 4; ++r) C[(long)(row + r) * ldc + col] = acc[mi][ni][r];
      } else if constexpr (MODE == 1) {
        f16* C = (f16*)Cv + (long)z * cOffZ;
#pragma unroll
        for (int r = 0; r < 4; ++r) C[(long)(row + r) * ldc + col] = (f16)acc[mi][ni][r];
      } else {  // MODE 2
        f16* C = (f16*)Cv + (long)z * cOffZ;
        f16x4 o = { (f16)acc[mi][ni][0], (f16)acc[mi][ni][1],
                    (f16)acc[mi][ni][2], (f16)acc[mi][ni][3] };
        *(f16x4*)(C + (long)col * ldc + row) = o;
      }
    }
  }
}

// ---------------------------------------------------------------------------
// Causal softmax over f16 score rows, in-place (zero above diagonal).
// grid = (SEQ, BATCH), block = 256, 8 contiguous elems/thread (f16x8).
// Loads skipped above the diagonal; WRITES only the ceil((q+1)/128)*128 cols
// that PV's per-m-tile K-limit actually reads (-15 MB writes).
// ---------------------------------------------------------------------------
__global__ __launch_bounds__(256) void softmax_causal(f16* S) {
  const int q = blockIdx.x, b = blockIdx.y;
  f16* row = S + ((long)b * SEQ + q) * SEQ;
  const int tid = threadIdx.x;
  const int lane = tid & 63, wave = tid >> 6;
  const int nvalid = q + 1;
  const int kneed  = ((q >> 7) + 1) << 7;  // cols PV reads for this row

  f16x8 vv = {};
  if (tid * 8 < nvalid) vv = *(const f16x8*)(row + tid * 8);
  float v[8];
  float m = -3.0e38f;
#pragma unroll
  for (int i = 0; i < 8; ++i) {
    const int k = tid * 8 + i;
    v[i] = (k < nvalid) ? (float)vv[i] * 0.03125f : -3.0e38f;
    m = fmaxf(m, v[i]);
  }
#pragma unroll
  for (int off = 32; off; off >>= 1) m = fmaxf(m, __shfl_xor(m, off));
  __shared__ float redm[4], reds[4];
  if (lane == 0) redm[wave] = m;
  __syncthreads();
  m = fmaxf(fmaxf(redm[0], redm[1]), fmaxf(redm[2], redm[3]));

  float s = 0.f;
#pragma unroll
  for (int i = 0; i < 8; ++i) {
    const float p = (v[i] > -1.0e37f) ? __expf(v[i] - m) : 0.f;
    v[i] = p;
    s += p;
  }
#pragma unroll
  for (int off = 32; off; off >>= 1) s += __shfl_xor(s, off);
  if (lane == 0) reds[wave] = s;
  __syncthreads();
  s = reds[0] + reds[1] + reds[2] + reds[3];
  const float inv = 1.f / s;
  f16x8 o;
#pragma unroll
  for (int i = 0; i < 8; ++i) o[i] = (f16)(v[i] * inv);
  if (tid * 8 < kneed) *(f16x8*)(row + tid * 8) = o;
}

// ---------------------------------------------------------------------------
extern "C" void kernel_launch(void* const* d_in, const int* in_sizes, int n_in,
                              void* d_out, int out_size, void* d_ws, size_t ws_size,
                              hipStream_t stream) {
  const float* x  = (const float*)d_in[0];
  const float* Wq = (const float*)d_in[1];
  const float* Wk = (const float*)d_in[2];
  const float* Wv = (const float*)d_in[3];
  float* out = (float*)d_out;

  // ws layout (f16 elems): xb 8M | Wh 3M | Qh 8M | Kh 8M | VT 8M ([1024][8192]) |
  //                        Sc 16M f16 scores->probs in place (4 x 2048 x 2048)
  if (ws_size < (size_t)51 * 1024 * 1024 * 2) return;

  f16* xb = (f16*)d_ws;
  f16* Wh = xb + (size_t)8 * 1024 * 1024;
  f16* Qh = Wh + (size_t)3 * 1024 * 1024;
  f16* Kh = Qh + (size_t)8 * 1024 * 1024;
  f16* VT = Kh + (size_t)8 * 1024 * 1024;
  f16* Sc = VT + (size_t)8 * 1024 * 1024;

  const long QOFF = (long)SEQ * DIM;  // per-batch Q/K offset
  const long SOFF = (long)SEQ * SEQ;  // per-batch score offset (f16 elems)

  cvt_all<<<11264, 256, 0, stream>>>(x, Wq, Wk, Wv, xb, Wh);

  // Fused QKV: M=8192, N=3072, K=1024 -- 256x192 tiles, 512 blocks = 2 exact
  // rounds, A-dbuf/B-tbuf counted-vmcnt pipeline.
  qkv_192<<<512, 512, 0, stream>>>(xb, Wh, Qh);

  // scores = Q K^T (causal block-skip), f16 out, BK=128 (grid-limited occupancy)
  gemm_bt<1, 1, 128><<<dim3(16, 16, 4), 256, 0, stream>>>(Qh, DIM, QOFF, Kh, DIM, QOFF,
                                                          Sc, SEQ, SOFF, DIM);

  // causal softmax (scale 1/32), in-place f16 probs, zero above diagonal
  softmax_causal<<<dim3(SEQ, BATCH), 256, 0, stream>>>(Sc);

  // Z = P V  (A = probs f16 ld 2048; B = VT ld 8192; per-M-tile K-limit),
  // BK=128 + balanced 1D grid (longest<->shortest pairing kills the Keff tail)
  gemm_bt<0, 3, 128><<<dim3(512, 1, 1), 256, 0, stream>>>(Sc, SEQ, SOFF,
                                                          VT, BATCH * SEQ, SEQ,
                                                          out, DIM, (long)SEQ * DIM, SEQ);
}